// Round 5
// baseline (9601.391 us; speedup 1.0000x reference)
//
#include <hip/hip_runtime.h>
#include <math.h>

#define TT   256
#define BB   1024
#define YDIM 32
#define HDIM 1024
#define RDIM 512

typedef __attribute__((ext_vector_type(8))) short frag8;
typedef __attribute__((ext_vector_type(4))) float f32x4;

// ---------------- workspace layout (bytes) ----------------
#define OFF_NLL   ((size_t)0)
#define OFF_HAF   ((size_t)4096)                     // fp32 h0 x2
#define SZ_HF     ((size_t)BB*RDIM*4)
#define OFF_HBF   (OFF_HAF + 2*SZ_HF)                // fp32 h1 x2
#define OFF_HA16  (OFF_HBF + 2*SZ_HF)                // bf16 h0 x2
#define SZ_H16    ((size_t)BB*RDIM*2)
#define OFF_HB16  (OFF_HA16 + 2*SZ_H16)              // bf16 h1 x2
#define OFF_D1    (OFF_HB16 + 2*SZ_H16)              // bf16 d1 x2
#define SZ_DBUF   ((size_t)BB*HDIM*2)
#define OFF_D2    (OFF_D1 + 2*SZ_DBUF)               // bf16 d2 x2
#define OFF_Y16   (OFF_D2 + 2*SZ_DBUF)               // bf16 y [T,B,32]
// round-2-validated packed GRU weights: 1536 rows, permRow interleave (16-unit granularity)
#define OFF_WG0I  (OFF_Y16 + (size_t)TT*BB*YDIM*2)   // [1536][32]
#define OFF_WG0H  (OFF_WG0I + (size_t)1536*YDIM*2)   // [1536][512]
#define OFF_WG1I  (OFF_WG0H + (size_t)1536*RDIM*2)   // [1536][512]
#define OFF_WG1H  (OFF_WG1I + (size_t)1536*RDIM*2)   // [1536][512]
#define OFF_WD1   (OFF_WG1H + (size_t)1536*RDIM*2)
#define OFF_WD2   (OFF_WD1 + (size_t)HDIM*RDIM*2)
#define OFF_WMS   (OFF_WD2 + (size_t)HDIM*HDIM*2)
#define OFF_BI0   (OFF_WMS + (size_t)64*HDIM*2)      // permuted biases, 1536 f32 each
#define OFF_BH0   (OFF_BI0 + 1536*4)
#define OFF_BI1   (OFF_BH0 + 1536*4)
#define OFF_BH1   (OFF_BI1 + 1536*4)

__device__ __forceinline__ short f2bf(float f) {
  union { float f; unsigned u; } v; v.f = f;
  unsigned r = (v.u + 0x7fffu + ((v.u >> 16) & 1u)) >> 16;
  return (short)r;
}
__device__ __forceinline__ void cvt8(const float* s, short* d) {
  float4 a = *(const float4*)s;
  float4 b = *(const float4*)(s + 4);
  frag8 v;
  v[0]=f2bf(a.x); v[1]=f2bf(a.y); v[2]=f2bf(a.z); v[3]=f2bf(a.w);
  v[4]=f2bf(b.x); v[5]=f2bf(b.y); v[6]=f2bf(b.z); v[7]=f2bf(b.w);
  *(frag8*)d = v;
}
// round-2-validated: packed row n' = q*48 + g*16 + u  <->  src row g*512 + q*16 + u
__device__ __forceinline__ int permRow(int n) {
  int q = n / 48, r = n - 48 * q, g = r >> 4, u = r & 15;
  return g * 512 + q * 16 + u;
}
__device__ __forceinline__ float sigf(float x) { return 1.0f / (1.0f + expf(-x)); }

// async 16B global -> LDS (dest = uniform base + lane*16)
__device__ __forceinline__ void gload16(const short* g, short* l) {
  __builtin_amdgcn_global_load_lds(
      (const __attribute__((address_space(1))) void*)g,
      (__attribute__((address_space(3))) void*)l, 16, 0, 0);
}

// ============ generic CW=32 double-buffered kloop (round-2 patterns) ============
template<int AROWS, int BROWS, int MF, int NF>
__device__ __forceinline__ void kloop32(
    const short* __restrict__ A, int lda, int m0,
    const short* __restrict__ B, int ldb, int K,
    int wm, int wn, short* lds, f32x4 (*acc)[NF], int tid)
{
  constexpr int BSTR = (AROWS + BROWS) * 32;
  const int l = tid & 63, w = tid >> 6, u = l & 15, quad = l >> 4;
  const int nk = K >> 5;

  auto stage = [&](int kc, short* buf) {
    const int k0 = kc << 5;
    for (int c = (w << 6); c < AROWS * 4; c += 256) {
      int p = c + l, r = p >> 2, q = (p & 3) ^ (r & 3);
      gload16(A + (size_t)(m0 + r) * lda + k0 + (q << 3), buf + (c << 3));
    }
    short* bb = buf + AROWS * 32;
    for (int c = (w << 6); c < BROWS * 4; c += 256) {
      int p = c + l, r = p >> 2, q = (p & 3) ^ (r & 3);
      gload16(B + (size_t)r * ldb + k0 + (q << 3), bb + (c << 3));
    }
  };

  stage(0, lds);
  __syncthreads();
  for (int kc = 0; kc < nk; ++kc) {
    if (kc + 1 < nk) stage(kc + 1, lds + ((kc + 1) & 1) * BSTR);
    const short* base = lds + (kc & 1) * BSTR;
    const int ao = (quad ^ (u & 3)) << 3;
    frag8 a[MF], b[NF];
#pragma unroll
    for (int i = 0; i < MF; ++i)
      a[i] = *(const frag8*)(base + (wm + (i << 4) + u) * 32 + ao);
#pragma unroll
    for (int f = 0; f < NF; ++f)
      b[f] = *(const frag8*)(base + AROWS * 32 + (wn + (f << 4) + u) * 32 + ao);
#pragma unroll
    for (int i = 0; i < MF; ++i)
#pragma unroll
      for (int f = 0; f < NF; ++f)
        acc[i][f] = __builtin_amdgcn_mfma_f32_16x16x32_bf16(a[i], b[f], acc[i][f], 0, 0, 0);
    __syncthreads();
  }
}

// ============ GRU kloop: A 128 rows, B = 192-row permRow-interleaved slice ============
// acc[4][2][4]: [a-frag i][unit16-group g][col: 0=r, 1=z, 2=ni, 3=nh].
// Gates r,z accumulate in cols 0,1 across BOTH passes; gate n goes to col NSEL.
template<int NSEL>
__device__ __forceinline__ void kloop_gru(
    const short* __restrict__ A, int lda, int m0,
    const short* __restrict__ B, int ldb, int K,
    short* lds, f32x4 (*acc)[2][4], int tid)
{
  constexpr int BSTR = (128 + 192) * 32;   // 10240 shorts
  const int l = tid & 63, w = tid >> 6, u = l & 15, quad = l >> 4;
  const int nk = K >> 5;
  const int wm = (w & 1) * 64;
  const int glb = (w >> 1) * 2;            // local unit16-group base for this wave

  auto stage = [&](int kc, short* buf) {
    const int k0 = kc << 5;
    for (int c = (w << 6); c < 512; c += 256) {
      int p = c + l, r = p >> 2, q = (p & 3) ^ (r & 3);
      gload16(A + (size_t)(m0 + r) * lda + k0 + (q << 3), buf + (c << 3));
    }
    short* bb = buf + 4096;
    for (int c = (w << 6); c < 768; c += 256) {
      int p = c + l, r = p >> 2, q = (p & 3) ^ (r & 3);
      gload16(B + (size_t)r * ldb + k0 + (q << 3), bb + (c << 3));
    }
  };

  stage(0, lds);
  __syncthreads();
  for (int kc = 0; kc < nk; ++kc) {
    if (kc + 1 < nk) stage(kc + 1, lds + ((kc + 1) & 1) * BSTR);
    const short* base = lds + (kc & 1) * BSTR;
    const short* bb = base + 4096;
    const int ao = (quad ^ (u & 3)) << 3;
    frag8 a[4], b[2][3];
#pragma unroll
    for (int i = 0; i < 4; ++i)
      a[i] = *(const frag8*)(base + (wm + (i << 4) + u) * 32 + ao);
#pragma unroll
    for (int g = 0; g < 2; ++g)
#pragma unroll
      for (int f = 0; f < 3; ++f)
        b[g][f] = *(const frag8*)(bb + (((glb + g) * 48 + f * 16 + u) * 32) + ao);
#pragma unroll
    for (int i = 0; i < 4; ++i)
#pragma unroll
      for (int g = 0; g < 2; ++g) {
        acc[i][g][0]    = __builtin_amdgcn_mfma_f32_16x16x32_bf16(a[i], b[g][0], acc[i][g][0], 0, 0, 0);
        acc[i][g][1]    = __builtin_amdgcn_mfma_f32_16x16x32_bf16(a[i], b[g][1], acc[i][g][1], 0, 0, 0);
        acc[i][g][NSEL] = __builtin_amdgcn_mfma_f32_16x16x32_bf16(a[i], b[g][2], acc[i][g][NSEL], 0, 0, 0);
      }
    __syncthreads();
  }
}

// ============ GRU tile: 128 rows x 64 units, two passes (x then h) ============
__device__ void gru5(int mb, int nb,
    const short* Ax, int ldax, int Kx,
    const short* Ah,
    const short* Wgi, int ldwi,
    const short* Wgh,
    const float* bi, const float* bh,
    const float* hold, float* hout, short* h16out,
    short* lds, int tid)
{
  const int w = tid >> 6, l = tid & 63, u = l & 15, quad = l >> 4;
  const int wm = (w & 1) * 64;
  f32x4 zero = {0.f, 0.f, 0.f, 0.f};
  f32x4 acc[4][2][4];
#pragma unroll
  for (int i = 0; i < 4; ++i)
#pragma unroll
    for (int g = 0; g < 2; ++g)
#pragma unroll
      for (int c = 0; c < 4; ++c) acc[i][g][c] = zero;

  kloop_gru<2>(Ax, ldax, mb * 128, Wgi, ldwi, Kx, lds, acc, tid);    // x pass: n -> ni
  kloop_gru<3>(Ah, RDIM, mb * 128, Wgh, RDIM, RDIM, lds, acc, tid);  // h pass: n -> nh

#pragma unroll
  for (int g = 0; g < 2; ++g) {
    const int gl = (w >> 1) * 2 + g;
    const int npg = nb * 192 + gl * 48 + u;
    const float bir = bi[npg], biz = bi[npg + 16], bin = bi[npg + 32];
    const float bhr = bh[npg], bhz = bh[npg + 16], bhn = bh[npg + 32];
    const int unit = nb * 64 + gl * 16 + u;
#pragma unroll
    for (int i = 0; i < 4; ++i)
#pragma unroll
      for (int j = 0; j < 4; ++j) {
        int row = mb * 128 + wm + 16 * i + quad * 4 + j;
        float rr = sigf((acc[i][g][0][j] + bir) + bhr);
        float zz = sigf((acc[i][g][1][j] + biz) + bhz);
        float nn = tanhf((acc[i][g][2][j] + bin) + rr * (acc[i][g][3][j] + bhn));
        float ho = hold[(size_t)row * RDIM + unit];
        float hv = (1.f - zz) * nn + zz * ho;
        hout[(size_t)row * RDIM + unit] = hv;
        h16out[(size_t)row * RDIM + unit] = f2bf(hv);
      }
  }
}

// ---------------- decoder Linear+ReLU tile (128x128) ----------------
__device__ void dec_tile(int mb, int nb, const short* A, int lda, int K,
                         const short* W, const float* bias, short* outp,
                         short* lds, int tid)
{
  f32x4 zero = {0.f, 0.f, 0.f, 0.f};
  f32x4 acc[4][4];
#pragma unroll
  for (int i = 0; i < 4; ++i)
#pragma unroll
    for (int f = 0; f < 4; ++f) acc[i][f] = zero;
  const int w = tid >> 6, l = tid & 63, u = l & 15, quad = l >> 4;
  const int wm = (w & 1) * 64, wn = (w >> 1) * 64;
  kloop32<128, 128, 4, 4>(A, lda, mb * 128, W, K, K, wm, wn, lds, acc, tid);
  const int colb = nb * 128 + wn + u;
  float bv[4];
#pragma unroll
  for (int f = 0; f < 4; ++f) bv[f] = bias[colb + 16 * f];
#pragma unroll
  for (int i = 0; i < 4; ++i)
#pragma unroll
    for (int f = 0; f < 4; ++f)
#pragma unroll
      for (int j = 0; j < 4; ++j) {
        int row = mb * 128 + wm + 16 * i + quad * 4 + j;
        float v = acc[i][f][j] + bv[f];
        if (v < 0.f) v = 0.f;
        outp[(size_t)row * HDIM + colb + 16 * f] = f2bf(v);
      }
}

// ---------------- mean/std + gaussian NLL tile ----------------
__device__ void ms_tile(int mb, int tstep, const short* d2p, const short* Wms,
                        const float* mbias, const float* sbias, const float* y,
                        float* nll, short* lds, int tid)
{
  f32x4 zero = {0.f, 0.f, 0.f, 0.f};
  f32x4 acc[2][4];
#pragma unroll
  for (int i = 0; i < 2; ++i)
#pragma unroll
    for (int f = 0; f < 4; ++f) acc[i][f] = zero;
  const int w = tid >> 6, l = tid & 63, u = l & 15, quad = l >> 4;
  kloop32<128, 64, 2, 4>(d2p, HDIM, mb * 128, Wms, HDIM, HDIM, w * 32, 0, lds, acc, tid);
  float lsum = 0.f;
#pragma unroll
  for (int i = 0; i < 2; ++i)
#pragma unroll
    for (int j = 0; j < 4; ++j) {
      int row = mb * 128 + w * 32 + 16 * i + quad * 4 + j;
      const float* yr = y + ((size_t)tstep * BB + row) * YDIM;
#pragma unroll
      for (int f = 0; f < 2; ++f) {
        int c = 16 * f + u;
        float m  = acc[i][f][j] + mbias[c];
        float sp = acc[i][f + 2][j] + sbias[c];
        float sg = (sp > 20.f) ? sp : log1pf(expf(sp));
        float dv = (yr[c] - m) / sg;
        lsum += dv * dv + 2.f * logf(sg) + 1.8378770664093453f;
      }
    }
  lsum *= 0.5f;
#pragma unroll
  for (int o = 32; o; o >>= 1) lsum += __shfl_xor(lsum, o);
  if (l == 0) atomicAdd(nll, lsum);
}

// ---------------- prepack (round-2 verbatim layouts) ----------------
__global__ __launch_bounds__(256) void prepack_kernel(
    const float* y, const float* dw1, const float* dw2,
    const float* mw, const float* sw,
    const float* wih0, const float* whh0, const float* bih0, const float* bhh0,
    const float* wih1, const float* whh1, const float* bih1, const float* bhh1,
    char* __restrict__ ws)
{
  const size_t g = (size_t)blockIdx.x * 256 + threadIdx.x;
  const size_t N = (size_t)gridDim.x * 256;
  float4 z4 = {0.f, 0.f, 0.f, 0.f};
  float4* hz = (float4*)(ws + OFF_HAF);
  for (size_t i = g; i < (size_t)4 * BB * RDIM / 4; i += N) hz[i] = z4;
  int4 zi = {0, 0, 0, 0};
  int4* h16z = (int4*)(ws + OFF_HA16);
  for (size_t i = g; i < (size_t)4 * BB * RDIM / 8; i += N) h16z[i] = zi;
  if (g == 0) *(float*)(ws + OFF_NLL) = 0.f;

  short* y16  = (short*)(ws + OFF_Y16);
  short* Wg0i = (short*)(ws + OFF_WG0I);
  short* Wg0h = (short*)(ws + OFF_WG0H);
  short* Wg1i = (short*)(ws + OFF_WG1I);
  short* Wg1h = (short*)(ws + OFF_WG1H);
  short* Wd1  = (short*)(ws + OFF_WD1);
  short* Wd2  = (short*)(ws + OFF_WD2);
  short* Wms  = (short*)(ws + OFF_WMS);
  float* bi0  = (float*)(ws + OFF_BI0);
  float* bh0  = (float*)(ws + OFF_BH0);
  float* bi1  = (float*)(ws + OFF_BI1);
  float* bh1  = (float*)(ws + OFF_BH1);

  for (size_t s = g; s < (size_t)TT * BB * YDIM / 8; s += N)
    cvt8(y + s * 8, y16 + s * 8);

  for (size_t s = g; s < (size_t)1536 * RDIM / 8; s += N) {
    int row = (int)(s >> 6), seg = (int)(s & 63) << 3;
    int pr = permRow(row);
    cvt8(whh0 + (size_t)pr * RDIM + seg, Wg0h + (size_t)row * RDIM + seg);
    cvt8(wih1 + (size_t)pr * RDIM + seg, Wg1i + (size_t)row * RDIM + seg);
    cvt8(whh1 + (size_t)pr * RDIM + seg, Wg1h + (size_t)row * RDIM + seg);
  }
  for (size_t s = g; s < (size_t)1536 * YDIM / 8; s += N) {
    int row = (int)(s >> 2), seg = (int)(s & 3) << 3;
    cvt8(wih0 + (size_t)permRow(row) * YDIM + seg, Wg0i + (size_t)row * YDIM + seg);
  }
  for (size_t s = g; s < (size_t)HDIM * RDIM / 8; s += N)
    cvt8(dw1 + s * 8, Wd1 + s * 8);
  for (size_t s = g; s < (size_t)HDIM * HDIM / 8; s += N)
    cvt8(dw2 + s * 8, Wd2 + s * 8);
  for (size_t s = g; s < (size_t)64 * HDIM / 8; s += N) {
    int row = (int)(s >> 7), seg = (int)(s & 127) << 3;
    const float* src = (row < 32) ? (mw + (size_t)row * HDIM + seg)
                                  : (sw + (size_t)(row - 32) * HDIM + seg);
    cvt8(src, Wms + (size_t)row * HDIM + seg);
  }
  for (size_t s = g; s < 1536; s += N) {
    int pr = permRow((int)s);
    bi0[s] = bih0[pr]; bh0[s] = bhh0[pr];
    bi1[s] = bih1[pr]; bh1[s] = bhh1[pr];
  }
}

// ---------------- one pipeline phase (grid = 264) ----------------
//  t [0,64)    : GRU1 128x64  -> h1_{p-1}   active 1<=p<=255
//  t [64,128)  : GRU0 128x64  -> h0_p       active p<=255
//  t [128,192) : D1 for step p-1            active 1<=p<=256
//  t [192,256) : D2 for step p-2            active 2<=p<=257
//  t [256,264) : MS/nll for step p-3        active 3<=p<=258
__global__ __launch_bounds__(256, 2) void phase_kernel(
    int p, const float* __restrict__ y,
    const float* db1, const float* db2, const float* mbias, const float* sbias,
    char* __restrict__ ws)
{
  __shared__ short lds[20480];   // 40 KB: GRU 2 x (128+192)*32 shorts
  const int tid = threadIdx.x;
  const int t = blockIdx.x;
  const int cur = p & 1, prv = cur ^ 1;

  float* hAf = (float*)(ws + OFF_HAF);
  float* hBf = (float*)(ws + OFF_HBF);
  short* hA16 = (short*)(ws + OFF_HA16);
  short* hB16 = (short*)(ws + OFF_HB16);
  short* d10 = (short*)(ws + OFF_D1);
  short* d20 = (short*)(ws + OFF_D2);
  const short* y16 = (const short*)(ws + OFF_Y16);

  float* hAfc = hAf + (size_t)cur * BB * RDIM;
  float* hAfp = hAf + (size_t)prv * BB * RDIM;
  float* hBfc = hBf + (size_t)cur * BB * RDIM;
  float* hBfp = hBf + (size_t)prv * BB * RDIM;
  short* hA16c = hA16 + (size_t)cur * BB * RDIM;
  short* hA16p = hA16 + (size_t)prv * BB * RDIM;
  short* hB16c = hB16 + (size_t)cur * BB * RDIM;
  short* hB16p = hB16 + (size_t)prv * BB * RDIM;
  short* d1c = d10 + (size_t)cur * BB * HDIM;
  short* d1p = d10 + (size_t)prv * BB * HDIM;
  short* d2c = d20 + (size_t)cur * BB * HDIM;
  short* d2p = d20 + (size_t)prv * BB * HDIM;

  const short* Wg0i = (const short*)(ws + OFF_WG0I);
  const short* Wg0h = (const short*)(ws + OFF_WG0H);
  const short* Wg1i = (const short*)(ws + OFF_WG1I);
  const short* Wg1h = (const short*)(ws + OFF_WG1H);
  const short* Wd1  = (const short*)(ws + OFF_WD1);
  const short* Wd2  = (const short*)(ws + OFF_WD2);
  const short* Wms  = (const short*)(ws + OFF_WMS);
  const float* bi0  = (const float*)(ws + OFF_BI0);
  const float* bh0  = (const float*)(ws + OFF_BH0);
  const float* bi1  = (const float*)(ws + OFF_BI1);
  const float* bh1  = (const float*)(ws + OFF_BH1);
  float* nllp = (float*)(ws + OFF_NLL);

  if (t < 64) {                     // GRU1: x = h0_{p-1}, h = h1_{p-2}
    if (p >= 1 && p <= 255) {
      int mb = t >> 3, nb = t & 7;
      gru5(mb, nb,
           hA16p, RDIM, RDIM,
           hB16p,
           Wg1i + (size_t)nb * 192 * RDIM, RDIM,
           Wg1h + (size_t)nb * 192 * RDIM,
           bi1, bh1, hBfp, hBfc, hB16c, lds, tid);
    }
  } else if (t < 128) {             // GRU0: x = y[p], h = h0_{p-1}
    if (p <= 255) {
      int q = t - 64, mb = q >> 3, nb = q & 7;
      gru5(mb, nb,
           y16 + (size_t)p * BB * YDIM, YDIM, YDIM,
           hA16p,
           Wg0i + (size_t)nb * 192 * YDIM, YDIM,
           Wg0h + (size_t)nb * 192 * RDIM,
           bi0, bh0, hAfp, hAfc, hA16c, lds, tid);
    }
  } else if (t < 192) {             // D1
    if (p >= 1 && p <= 256) {
      int q = t - 128, mb = q >> 3, nb = q & 7;
      dec_tile(mb, nb, hB16p, RDIM, RDIM, Wd1 + (size_t)nb * 128 * RDIM,
               db1, d1c, lds, tid);
    }
  } else if (t < 256) {             // D2
    if (p >= 2 && p <= 257) {
      int q = t - 192, mb = q >> 3, nb = q & 7;
      dec_tile(mb, nb, d1p, HDIM, HDIM, Wd2 + (size_t)nb * 128 * HDIM,
               db2, d2c, lds, tid);
    }
  } else {                          // MS
    if (p >= 3 && p <= 258) {
      ms_tile(t - 256, p - 3, d2p, Wms, mbias, sbias, y, nllp, lds, tid);
    }
  }
}

__global__ void finish_kernel(float* out, const char* ws)
{
  if (threadIdx.x == 0 && blockIdx.x == 0)
    out[0] = *(const float*)(ws + OFF_NLL);
}

extern "C" void kernel_launch(void* const* d_in, const int* in_sizes, int n_in,
                              void* d_out, int out_size, void* d_ws, size_t ws_size,
                              hipStream_t stream) {
  (void)in_sizes; (void)n_in; (void)out_size; (void)ws_size;
  const float* y    = (const float*)d_in[0];
  const float* dw1  = (const float*)d_in[1];
  const float* db1  = (const float*)d_in[2];
  const float* dw2  = (const float*)d_in[3];
  const float* db2  = (const float*)d_in[4];
  const float* mw   = (const float*)d_in[5];
  const float* mbias= (const float*)d_in[6];
  const float* sw   = (const float*)d_in[7];
  const float* sbias= (const float*)d_in[8];
  const float* wih0 = (const float*)d_in[9];
  const float* whh0 = (const float*)d_in[10];
  const float* bih0 = (const float*)d_in[11];
  const float* bhh0 = (const float*)d_in[12];
  const float* wih1 = (const float*)d_in[13];
  const float* whh1 = (const float*)d_in[14];
  const float* bih1 = (const float*)d_in[15];
  const float* bhh1 = (const float*)d_in[16];
  char* ws = (char*)d_ws;
  float* out = (float*)d_out;

  prepack_kernel<<<256, 256, 0, stream>>>(y, dw1, dw2, mw, sw,
                                          wih0, whh0, bih0, bhh0,
                                          wih1, whh1, bih1, bhh1, ws);
  for (int p = 0; p < 259; ++p)
    phase_kernel<<<264, 256, 0, stream>>>(p, y, db1, db2, mbias, sbias, ws);
  finish_kernel<<<1, 1, 0, stream>>>(out, ws);
}